// Round 2
// 635.083 us; speedup vs baseline: 1.1147x; 1.1147x over previous
//
#include <hip/hip_runtime.h>

// Problem: B=16384, S=32, E=128, H=4, DH=32, O=128. fp32 in/out.
// Split-fp32 (bf16 hi+lo, 3-product MFMA) on v_mfma_f32_16x16x32_bf16.
//
// This revision vs 450us baseline:
//  - Weight staging via __builtin_amdgcn_global_load_lds (async DMA, no VGPR
//    hop, no copy16 VALU). prep_w writes weights in a 16B-granule XOR-swizzled
//    layout so the *linear* DMA placement gives conflict-free frag reads.
//  - Raw s_barrier with split waits: issue next weight tile right after the
//    read-retire barrier, overlap its L2 flight with the previous projection's
//    C-frag writeback, wait vmcnt(0) only at the consume barrier.
//  - All fp32->bf16 conversions via HW cvt ((__bf16) cast -> v_cvt_pk_bf16_f32,
//    RNE — bit-identical to integer round-to-nearest-even f2bf).
//  - Dedicated A region (no K aliasing) removes one sync pair per head.
//
// ws layout (unsigned short), 262144 B total:
//   tile(t,h) base = ((t*4+h) * 8192) shorts; hi at [0..4095], lo at [4096..8191]
//   t in {0=wq,1=wk,2=wv}: logical [n=d(32)][k=e(128)],
//     phys = n*128 + (((k>>3) ^ (n&15))<<3) + (k&7)
//   t=3 (wo): logical [n=o(128)][k=dh(32)],
//     phys = n*32 + (((k>>3) ^ ((n>>1)&3))<<3) + (k&7)
//   scale 1/sqrt(32) folded into wq.

typedef __bf16 bf16x8 __attribute__((ext_vector_type(8)));
typedef __bf16 bf16x2 __attribute__((ext_vector_type(2)));
typedef float f32x4 __attribute__((ext_vector_type(4)));

union FragU { unsigned int w[4]; bf16x8 v; };

__device__ inline unsigned short f2bf(float f) {
  return __builtin_bit_cast(unsigned short, (__bf16)f);  // HW cvt, RNE
}
__device__ inline float bf2f(unsigned short h) {
  return __builtin_bit_cast(float, (unsigned int)h << 16);
}

__device__ inline bf16x8 ld_frag8(const unsigned short* p) {
  // 8 consecutive bf16, 8-byte aligned -> two ds_read_b64
  FragU f;
  const uint2* q = (const uint2*)p;
  uint2 a = q[0], b = q[1];
  f.w[0] = a.x; f.w[1] = a.y; f.w[2] = b.x; f.w[3] = b.y;
  return f.v;
}
__device__ inline bf16x8 ld_frag16(const unsigned short* p) {
  // 16-byte aligned -> one ds_read_b128
  FragU f;
  uint4 a = *(const uint4*)p;
  f.w[0] = a.x; f.w[1] = a.y; f.w[2] = a.z; f.w[3] = a.w;
  return f.v;
}

__device__ inline f32x4 mfma16(bf16x8 a, bf16x8 b, f32x4 c) {
  return __builtin_amdgcn_mfma_f32_16x16x32_bf16(a, b, c, 0, 0, 0);
}

__device__ inline void wb_pair(unsigned short* dhi, unsigned short* dlo, float v) {
  __bf16 h = (__bf16)v;
  *dhi = __builtin_bit_cast(unsigned short, h);
  *dlo = f2bf(v - (float)h);
}

// Raw barriers. Leading asm: drain the required counters (stores/reads retire)
// and fence sinking; trailing empty asm: fence hoisting of post-barrier loads
// above the barrier (bare s_barrier is not a memory code-motion fence).
#define SYNC_LDS() do { asm volatile("s_waitcnt lgkmcnt(0)" ::: "memory"); \
                        __builtin_amdgcn_s_barrier(); \
                        asm volatile("" ::: "memory"); } while (0)
#define SYNC_VM()  do { asm volatile("s_waitcnt vmcnt(0) lgkmcnt(0)" ::: "memory"); \
                        __builtin_amdgcn_s_barrier(); \
                        asm volatile("" ::: "memory"); } while (0)

// Stage one 16 KB weight tile (hi+lo) global->LDS[0..16383] via async DMA.
// Each wave stages its own 4 KB chunk: 4 issues x (64 lanes x 16 B).
// LDS dest is wave-uniform base + lane*16 (HW rule); widu is readfirstlane'd
// so the backend provably has an SGPR for m0.
__device__ inline void stage4(const unsigned short* wt, unsigned short* ldsb,
                              int widu, int lane) {
  const char* g = (const char*)wt + (widu << 12) + (lane << 4);
  char* l = (char*)ldsb + (widu << 12);
#pragma unroll
  for (int j = 0; j < 4; ++j) {
    __builtin_amdgcn_global_load_lds(
        (const __attribute__((address_space(1))) void*)(g + (j << 10)),
        (__attribute__((address_space(3))) void*)(l + (j << 10)),
        16, 0, 0);
  }
}

// Projection: c0/c1 += x * W^T (3-product split), frag reads swizzle-matched
// to prep_w's layout. Granule g=(kk*4+quad); row n: phys granule = g ^ (n&15).
__device__ inline void proj3(const unsigned short* lds, int col, int quad,
                             const bf16x8* xh, const bf16x8* xl,
                             f32x4& c0, f32x4& c1) {
#pragma unroll
  for (int kk = 0; kk < 4; ++kk) {
    int swz = ((((kk << 2) | quad) ^ col) << 3);
    const unsigned short* ph = lds + (col << 7) + swz;
    bf16x8 f0 = ld_frag16(ph);           // hi, row col
    bf16x8 f1 = ld_frag16(ph + 2048);    // hi, row col+16 (same swz: (n+16)&15==col)
    bf16x8 g0 = ld_frag16(ph + 4096);    // lo, row col
    bf16x8 g1 = ld_frag16(ph + 6144);    // lo, row col+16
    c0 = mfma16(xh[kk], f0, c0); c0 = mfma16(xl[kk], f0, c0); c0 = mfma16(xh[kk], g0, c0);
    c1 = mfma16(xh[kk], f1, c1); c1 = mfma16(xl[kk], f1, c1); c1 = mfma16(xh[kk], g1, c1);
  }
}

// ---------------- weight prep: fp32 -> swizzled bf16 hi/lo tiles ------------
__global__ void prep_w(const float* __restrict__ wq, const float* __restrict__ wk,
                       const float* __restrict__ wv, const float* __restrict__ wo,
                       unsigned short* __restrict__ wsb) {
  int idx = blockIdx.x * 256 + threadIdx.x;     // 0..65535
  int t = idx >> 14;
  int rem = idx & 16383;
  int hh = rem >> 12;
  int r2 = rem & 4095;
  const float* src = (t == 0) ? wq : (t == 1) ? wk : (t == 2) ? wv : wo;
  float v = src[rem];
  if (t == 0) v *= 0.17677669529663687f;        // 1/sqrt(32)
  int phys;
  if (t < 3) {
    int e = r2 >> 5, d = r2 & 31;               // n=d, k=e
    phys = (d << 7) + (((e >> 3) ^ (d & 15)) << 3) + (e & 7);
  } else {
    int dh = r2 >> 7, o = r2 & 127;             // n=o, k=dh
    phys = (o << 5) + (((dh >> 3) ^ ((o >> 1) & 3)) << 3) + (dh & 7);
  }
  int base = ((t << 2) | hh) << 13;
  __bf16 h = (__bf16)v;
  wsb[base + phys] = __builtin_bit_cast(unsigned short, h);
  wsb[base + 4096 + phys] = f2bf(v - (float)h);
}

// ---------------- main fused attention ----------------
// LDS map (shorts). WB is swizzled-linear (DMA target); scratch stays [36]-pad.
#define OFF_WB_HI 0         // 4096: proj [32][128]swz or wo [128][32]swz, hi
#define OFF_WB_LO 4096      // 4096: lo
#define OFF_A     8192      // [2][32][36] softmax A (dedicated; no aliasing)
#define OFF_K_HI  10496     // [2][32][36]
#define OFF_K_LO  12800
#define OFF_VT_HI 15104     // V^T [2][32 d][36 t]
#define OFF_VT_LO 17408
#define OFF_Q_HI  19712     // [2][2][16][36] (Hd aliases after scores)
#define OFF_Q_LO  22016
#define LDS_TOT   24320     // 48640 B -> 3 blocks/CU

__global__ __launch_bounds__(256, 3) void attn_fused(
    const float* __restrict__ x, const unsigned short* __restrict__ wsb,
    float* __restrict__ out) {
  __shared__ __align__(16) unsigned short lds[LDS_TOT];
  const int tid = threadIdx.x;
  const int lane = tid & 63;
  const int wid = tid >> 6;       // 4 waves
  const int widu = __builtin_amdgcn_readfirstlane(wid);  // provably wave-uniform
  const int bl = wid >> 1;        // local batch 0/1
  const int hw = wid & 1;         // 16-row half
  const int sbase = hw << 4;
  const int col = lane & 15;
  const int quad = lane >> 4;

  // ---- stage x -> hi/lo A-fragments in registers (rows sbase..sbase+15) ----
  bf16x8 xh[4], xl[4];
  for (int b = 0; b < 2; ++b) {
    const float4* xg = (const float4*)(x + ((long)(blockIdx.x * 2 + b) << 12));
#pragma unroll
    for (int it = 0; it < 4; ++it) {
      int f4 = it * 256 + tid;
      float4 v = xg[f4];
      int s = f4 >> 5;
      int e = (f4 & 31) << 2;
      __bf16 h0 = (__bf16)v.x, h1 = (__bf16)v.y, h2 = (__bf16)v.z, h3 = (__bf16)v.w;
      bf16x2 hp0 = {h0, h1}, hp1 = {h2, h3};
      bf16x2 lp0 = {(__bf16)(v.x - (float)h0), (__bf16)(v.y - (float)h1)};
      bf16x2 lp1 = {(__bf16)(v.z - (float)h2), (__bf16)(v.w - (float)h3)};
      uint2 ph = {__builtin_bit_cast(unsigned int, hp0), __builtin_bit_cast(unsigned int, hp1)};
      uint2 pl = {__builtin_bit_cast(unsigned int, lp0), __builtin_bit_cast(unsigned int, lp1)};
      *(uint2*)(lds + s * 132 + e) = ph;          // hi tile [32][132] at 0
      *(uint2*)(lds + 4224 + s * 132 + e) = pl;   // lo tile at 4224
    }
    __syncthreads();
    if (bl == b) {
#pragma unroll
      for (int kk = 0; kk < 4; ++kk) {
        xh[kk] = ld_frag8(lds + (sbase + col) * 132 + (kk << 5) + (quad << 3));
        xl[kk] = ld_frag8(lds + 4224 + (sbase + col) * 132 + (kk << 5) + (quad << 3));
      }
    }
    __syncthreads();
  }

  const long batch = (long)blockIdx.x * 2 + bl;
  const f32x4 zero = {0.f, 0.f, 0.f, 0.f};
  f32x4 oacc[8];
#pragma unroll
  for (int i = 0; i < 8; ++i) oacc[i] = zero;

  unsigned short* Kh = lds + OFF_K_HI + bl * 1152;
  unsigned short* Kl = lds + OFF_K_LO + bl * 1152;
  unsigned short* Vh = lds + OFF_VT_HI + bl * 1152;
  unsigned short* Vl = lds + OFF_VT_LO + bl * 1152;
  unsigned short* Qh = lds + OFF_Q_HI + (bl * 2 + hw) * 576;
  unsigned short* Ql = lds + OFF_Q_LO + (bl * 2 + hw) * 576;
  unsigned short* Abuf = lds + OFF_A + bl * 1152;

  for (int hh = 0; hh < 4; ++hh) {
    // T0: prev head's wo reads retired -> stage wq
    SYNC_LDS();
    stage4(wsb + (hh << 13), lds, widu, lane);              // wq(h)
    SYNC_VM();

    // ======== Q = x * WqT ========
    f32x4 c0 = zero, c1 = zero;
    __builtin_amdgcn_s_setprio(1);
    proj3(lds, col, quad, xh, xl, c0, c1);
    __builtin_amdgcn_s_setprio(0);

    SYNC_LDS();                                             // wq reads retired
    stage4(wsb + ((4 + hh) << 13), lds, widu, lane);        // wk (flight hides under WB)
#pragma unroll
    for (int r = 0; r < 4; ++r) {                           // writeback Q (own region)
      int row = (quad << 2) + r;
      wb_pair(Qh + row * 36 + col, Ql + row * 36 + col, c0[r]);
      wb_pair(Qh + row * 36 + col + 16, Ql + row * 36 + col + 16, c1[r]);
    }
    SYNC_VM();

    // ======== K = x * WkT ========
    c0 = zero; c1 = zero;
    __builtin_amdgcn_s_setprio(1);
    proj3(lds, col, quad, xh, xl, c0, c1);
    __builtin_amdgcn_s_setprio(0);

    SYNC_LDS();
    stage4(wsb + ((8 + hh) << 13), lds, widu, lane);        // wv
#pragma unroll
    for (int r = 0; r < 4; ++r) {                           // writeback K (own half rows)
      int row = sbase + (quad << 2) + r;
      wb_pair(Kh + row * 36 + col, Kl + row * 36 + col, c0[r]);
      wb_pair(Kh + row * 36 + col + 16, Kl + row * 36 + col + 16, c1[r]);
    }
    SYNC_VM();                                              // also publishes K

    // ======== V = x * WvT ========
    c0 = zero; c1 = zero;
    __builtin_amdgcn_s_setprio(1);
    proj3(lds, col, quad, xh, xl, c0, c1);
    __builtin_amdgcn_s_setprio(0);

    SYNC_LDS();
    stage4(wsb + ((12 + hh) << 13), lds, widu, lane);       // wo
#pragma unroll
    for (int r = 0; r < 4; ++r) {                           // writeback V^T (own t cols)
      int t = sbase + (quad << 2) + r;
      wb_pair(Vh + col * 36 + t, Vl + col * 36 + t, c0[r]);
      wb_pair(Vh + (col + 16) * 36 + t, Vl + (col + 16) * 36 + t, c1[r]);
    }

    // ======== scores = Q*K^T (overlaps wo flight) ========
    f32x4 s0 = zero, s1 = zero;
    {
      bf16x8 qhf = ld_frag8(Qh + col * 36 + (quad << 3));
      bf16x8 qlf = ld_frag8(Ql + col * 36 + (quad << 3));
      bf16x8 k0 = ld_frag8(Kh + col * 36 + (quad << 3));
      bf16x8 k1 = ld_frag8(Kh + (col + 16) * 36 + (quad << 3));
      bf16x8 k0l = ld_frag8(Kl + col * 36 + (quad << 3));
      bf16x8 k1l = ld_frag8(Kl + (col + 16) * 36 + (quad << 3));
      s0 = mfma16(qhf, k0, s0); s0 = mfma16(qlf, k0, s0); s0 = mfma16(qhf, k0l, s0);
      s1 = mfma16(qhf, k1, s1); s1 = mfma16(qlf, k1, s1); s1 = mfma16(qhf, k1l, s1);
    }
    // ======== softmax over t, in C-frag registers ========
    float a0[4], a1[4];
#pragma unroll
    for (int r = 0; r < 4; ++r) {
      float v0 = s0[r], v1 = s1[r];
      float mx = fmaxf(v0, v1);
#pragma unroll
      for (int dx = 1; dx < 16; dx <<= 1) mx = fmaxf(mx, __shfl_xor(mx, dx));
      float e0 = __expf(v0 - mx), e1 = __expf(v1 - mx);
      float sm = e0 + e1;
#pragma unroll
      for (int dx = 1; dx < 16; dx <<= 1) sm += __shfl_xor(sm, dx);
      float inv = 1.0f / sm;
      a0[r] = e0 * inv; a1[r] = e1 * inv;
    }
#pragma unroll
    for (int r = 0; r < 4; ++r) {                           // A: dedicated region, own rows
      int row = sbase + (quad << 2) + r;
      Abuf[row * 36 + col] = f2bf(a0[r]);
      Abuf[row * 36 + col + 16] = f2bf(a1[r]);
    }
    SYNC_VM();                                              // publishes V^T + A + wo staged

    // ======== Hd = A * V ========
    f32x4 hv0 = zero, hv1 = zero;
    {
      bf16x8 af = ld_frag8(Abuf + (sbase + col) * 36 + (quad << 3));
      bf16x8 v0h = ld_frag8(Vh + col * 36 + (quad << 3));
      bf16x8 v1h = ld_frag8(Vh + (col + 16) * 36 + (quad << 3));
      bf16x8 v0l = ld_frag8(Vl + col * 36 + (quad << 3));
      bf16x8 v1l = ld_frag8(Vl + (col + 16) * 36 + (quad << 3));
      hv0 = mfma16(af, v0h, hv0); hv0 = mfma16(af, v0l, hv0);
      hv1 = mfma16(af, v1h, hv1); hv1 = mfma16(af, v1l, hv1);
    }
#pragma unroll
    for (int r = 0; r < 4; ++r) {                           // Hd into dead Q region (own)
      int row = (quad << 2) + r;
      wb_pair(Qh + row * 36 + col, Ql + row * 36 + col, hv0[r]);
      wb_pair(Qh + row * 36 + col + 16, Ql + row * 36 + col + 16, hv1[r]);
    }
    // ======== out += Hd * Wo ========
    {
      bf16x8 dh = ld_frag8(Qh + col * 36 + (quad << 3));
      bf16x8 dl = ld_frag8(Ql + col * 36 + (quad << 3));
      int swzo = (quad ^ ((col >> 1) & 3)) << 3;
      __builtin_amdgcn_s_setprio(1);
#pragma unroll
      for (int t8 = 0; t8 < 8; ++t8) {
        const unsigned short* wp = lds + (((t8 << 4) + col) << 5) + swzo;
        bf16x8 wh = ld_frag16(wp);
        bf16x8 wl = ld_frag16(wp + 4096);
        oacc[t8] = mfma16(dh, wh, oacc[t8]);
        oacc[t8] = mfma16(dl, wh, oacc[t8]);
        oacc[t8] = mfma16(dh, wl, oacc[t8]);
      }
      __builtin_amdgcn_s_setprio(0);
    }
  }  // head loop

  // ---- store out [16 rows][128 cols] fp32 ----
  float* og = out + batch * 4096;
#pragma unroll
  for (int t8 = 0; t8 < 8; ++t8) {
#pragma unroll
    for (int r = 0; r < 4; ++r) {
      og[(sbase + (quad << 2) + r) * 128 + (t8 << 4) + col] = oacc[t8][r];
    }
  }
}

extern "C" void kernel_launch(void* const* d_in, const int* in_sizes, int n_in,
                              void* d_out, int out_size, void* d_ws, size_t ws_size,
                              hipStream_t stream) {
  const float* x = (const float*)d_in[0];
  const float* wq = (const float*)d_in[1];
  const float* wk = (const float*)d_in[2];
  const float* wv = (const float*)d_in[3];
  const float* wo = (const float*)d_in[4];
  float* out = (float*)d_out;
  unsigned short* wsb = (unsigned short*)d_ws;  // needs 262144 B
  hipLaunchKernelGGL(prep_w, dim3(256), dim3(256), 0, stream, wq, wk, wv, wo, wsb);
  hipLaunchKernelGGL(attn_fused, dim3(8192), dim3(256), 0, stream, x, wsb, out);
}

// Round 3
// 598.141 us; speedup vs baseline: 1.1836x; 1.0618x over previous
//
#include <hip/hip_runtime.h>

// Problem: B=16384, S=32, E=128, H=4, DH=32, O=128. fp32 in/out.
// Split-fp32 (bf16 hi+lo, 3-product MFMA) on v_mfma_f32_16x16x32_bf16.
//
// Round-3 changes vs 366us round-2 kernel (LDS-pipe-bound: ~80% DS occupancy):
//  - N-SPLIT projections: each wave of a batch computes ALL 32 rows x its
//    16-col half. Weight frag reads halve (8 b128/tensor vs 16). x A-frags
//    for both 16-row tiles held in VGPRs (64 regs, loaded once).
//  - V^T writeback packed: lane's 4 acc rows are consecutive t in [d][t]
//    layout -> one ds_write_b64 hi + one lo per M-tile (was 8 ds_write_b16).
//  - Softmax reduce via DPP (quad_perm xor1/xor2 + row_ror:4/8) - pure VALU,
//    no ds_swizzle.
//  Schedule/barriers/staging/numerics identical to round 2.
//
// ws layout (unsigned short), 262144 B total:
//   tile(t,h) base = ((t*4+h) * 8192) shorts; hi at [0..4095], lo at [4096..8191]
//   t in {0=wq,1=wk,2=wv}: logical [n=d(32)][k=e(128)],
//     phys = n*128 + (((k>>3) ^ (n&15))<<3) + (k&7)
//   t=3 (wo): logical [n=o(128)][k=dh(32)],
//     phys = n*32 + (((k>>3) ^ ((n>>1)&3))<<3) + (k&7)
//   scale 1/sqrt(32) folded into wq.

typedef __bf16 bf16x8 __attribute__((ext_vector_type(8)));
typedef __bf16 bf16x2 __attribute__((ext_vector_type(2)));
typedef float f32x4 __attribute__((ext_vector_type(4)));

union FragU { unsigned int w[4]; bf16x8 v; };

__device__ inline unsigned short f2bf(float f) {
  return __builtin_bit_cast(unsigned short, (__bf16)f);  // HW cvt, RNE
}
__device__ inline float bf2f(unsigned short h) {
  return __builtin_bit_cast(float, (unsigned int)h << 16);
}

__device__ inline bf16x8 ld_frag8(const unsigned short* p) {
  FragU f;
  const uint2* q = (const uint2*)p;
  uint2 a = q[0], b = q[1];
  f.w[0] = a.x; f.w[1] = a.y; f.w[2] = b.x; f.w[3] = b.y;
  return f.v;
}
__device__ inline bf16x8 ld_frag16(const unsigned short* p) {
  FragU f;
  uint4 a = *(const uint4*)p;
  f.w[0] = a.x; f.w[1] = a.y; f.w[2] = a.z; f.w[3] = a.w;
  return f.v;
}

__device__ inline f32x4 mfma16(bf16x8 a, bf16x8 b, f32x4 c) {
  return __builtin_amdgcn_mfma_f32_16x16x32_bf16(a, b, c, 0, 0, 0);
}

__device__ inline void wb_pair(unsigned short* dhi, unsigned short* dlo, float v) {
  __bf16 h = (__bf16)v;
  *dhi = __builtin_bit_cast(unsigned short, h);
  *dlo = f2bf(v - (float)h);
}

// ---- DPP 16-lane reductions (pure VALU; lanes 0-15/16-31/... are DPP rows) --
template <int CTRL>
__device__ inline float dppf(float x) {
  return __builtin_bit_cast(float,
      __builtin_amdgcn_update_dpp(0, __builtin_bit_cast(int, x), CTRL, 0xF, 0xF, true));
}
__device__ inline float rowmax16(float v) {
  v = fmaxf(v, dppf<0xB1>(v));   // quad_perm(1,0,3,2)  = xor 1
  v = fmaxf(v, dppf<0x4E>(v));   // quad_perm(2,3,0,1)  = xor 2
  v = fmaxf(v, dppf<0x124>(v));  // row_ror:4  (covers other quad-pair)
  v = fmaxf(v, dppf<0x128>(v));  // row_ror:8
  return v;
}
__device__ inline float rowsum16(float v) {
  v += dppf<0xB1>(v);
  v += dppf<0x4E>(v);
  v += dppf<0x124>(v);
  v += dppf<0x128>(v);
  return v;
}

// Raw barriers: split waits; trailing asm fences hoisting past the barrier.
#define SYNC_LDS() do { asm volatile("s_waitcnt lgkmcnt(0)" ::: "memory"); \
                        __builtin_amdgcn_s_barrier(); \
                        asm volatile("" ::: "memory"); } while (0)
#define SYNC_VM()  do { asm volatile("s_waitcnt vmcnt(0) lgkmcnt(0)" ::: "memory"); \
                        __builtin_amdgcn_s_barrier(); \
                        asm volatile("" ::: "memory"); } while (0)

// Stage one 16 KB weight tile (hi+lo) global->LDS[0..16383] via async DMA.
__device__ inline void stage4(const unsigned short* wt, unsigned short* ldsb,
                              int widu, int lane) {
  const char* g = (const char*)wt + (widu << 12) + (lane << 4);
  char* l = (char*)ldsb + (widu << 12);
#pragma unroll
  for (int j = 0; j < 4; ++j) {
    __builtin_amdgcn_global_load_lds(
        (const __attribute__((address_space(1))) void*)(g + (j << 10)),
        (__attribute__((address_space(3))) void*)(l + (j << 10)),
        16, 0, 0);
  }
}

// N-split projection: c0 (rows 0..15) / c1 (rows 16..31) += x * W^T for this
// wave's 16-col half (z). Reads 8 b128 per tensor (half the tile).
__device__ inline void projNS(const unsigned short* wb, int col, int quad, int z,
                              const bf16x8 xh[2][4], const bf16x8 xl[2][4],
                              f32x4& c0, f32x4& c1) {
#pragma unroll
  for (int kk = 0; kk < 4; ++kk) {
    int swz = ((((kk << 2) | quad) ^ col) << 3);
    const unsigned short* ph = wb + (((z << 4) + col) << 7) + swz;
    bf16x8 f = ld_frag16(ph);           // hi, row n = z*16+col
    bf16x8 g = ld_frag16(ph + 4096);    // lo
    c0 = mfma16(xh[0][kk], f, c0); c0 = mfma16(xl[0][kk], f, c0); c0 = mfma16(xh[0][kk], g, c0);
    c1 = mfma16(xh[1][kk], f, c1); c1 = mfma16(xl[1][kk], f, c1); c1 = mfma16(xh[1][kk], g, c1);
  }
}

// ---------------- weight prep: fp32 -> swizzled bf16 hi/lo tiles ------------
__global__ void prep_w(const float* __restrict__ wq, const float* __restrict__ wk,
                       const float* __restrict__ wv, const float* __restrict__ wo,
                       unsigned short* __restrict__ wsb) {
  int idx = blockIdx.x * 256 + threadIdx.x;     // 0..65535
  int t = idx >> 14;
  int rem = idx & 16383;
  int hh = rem >> 12;
  int r2 = rem & 4095;
  const float* src = (t == 0) ? wq : (t == 1) ? wk : (t == 2) ? wv : wo;
  float v = src[rem];
  if (t == 0) v *= 0.17677669529663687f;        // 1/sqrt(32)
  int phys;
  if (t < 3) {
    int e = r2 >> 5, d = r2 & 31;               // n=d, k=e
    phys = (d << 7) + (((e >> 3) ^ (d & 15)) << 3) + (e & 7);
  } else {
    int dh = r2 >> 7, o = r2 & 127;             // n=o, k=dh
    phys = (o << 5) + (((dh >> 3) ^ ((o >> 1) & 3)) << 3) + (dh & 7);
  }
  int base = ((t << 2) | hh) << 13;
  __bf16 h = (__bf16)v;
  wsb[base + phys] = __builtin_bit_cast(unsigned short, h);
  wsb[base + 4096 + phys] = f2bf(v - (float)h);
}

// ---------------- main fused attention ----------------
// LDS map (shorts). WB is swizzled-linear (DMA target); scratch [36]-padded.
#define OFF_WB_HI 0         // 4096: proj [32][128]swz or wo [128][32]swz, hi
#define OFF_WB_LO 4096      // 4096: lo
#define OFF_A     8192      // [2][32][36] softmax A
#define OFF_K_HI  10496     // [2][32][36]
#define OFF_K_LO  12800
#define OFF_VT_HI 15104     // V^T [2][32 d][36 t]
#define OFF_VT_LO 17408
#define OFF_Q_HI  19712     // [2][32][36]  (Hd aliases own rows after scores)
#define OFF_Q_LO  22016
#define LDS_TOT   24320     // 48640 B -> 3 blocks/CU

__global__ __launch_bounds__(256, 3) void attn_fused(
    const float* __restrict__ x, const unsigned short* __restrict__ wsb,
    float* __restrict__ out) {
  __shared__ __align__(16) unsigned short lds[LDS_TOT];
  const int tid = threadIdx.x;
  const int lane = tid & 63;
  const int wid = tid >> 6;       // 4 waves
  const int widu = __builtin_amdgcn_readfirstlane(wid);
  const int bl = wid >> 1;        // local batch 0/1
  const int hw = wid & 1;         // N-half for proj, M-half for attention
  const int sbase = hw << 4;
  const int col = lane & 15;
  const int quad = lane >> 4;

  // ---- stage x -> hi/lo A-fragments in registers (ALL 32 rows, 2 M-tiles) --
  bf16x8 xh[2][4], xl[2][4];
  for (int b = 0; b < 2; ++b) {
    const float4* xg = (const float4*)(x + ((long)(blockIdx.x * 2 + b) << 12));
#pragma unroll
    for (int it = 0; it < 4; ++it) {
      int f4 = it * 256 + tid;
      float4 v = xg[f4];
      int s = f4 >> 5;
      int e = (f4 & 31) << 2;
      __bf16 h0 = (__bf16)v.x, h1 = (__bf16)v.y, h2 = (__bf16)v.z, h3 = (__bf16)v.w;
      bf16x2 hp0 = {h0, h1}, hp1 = {h2, h3};
      bf16x2 lp0 = {(__bf16)(v.x - (float)h0), (__bf16)(v.y - (float)h1)};
      bf16x2 lp1 = {(__bf16)(v.z - (float)h2), (__bf16)(v.w - (float)h3)};
      uint2 ph = {__builtin_bit_cast(unsigned int, hp0), __builtin_bit_cast(unsigned int, hp1)};
      uint2 pl = {__builtin_bit_cast(unsigned int, lp0), __builtin_bit_cast(unsigned int, lp1)};
      *(uint2*)(lds + s * 132 + e) = ph;          // hi tile [32][132] at 0
      *(uint2*)(lds + 4224 + s * 132 + e) = pl;   // lo tile at 4224
    }
    __syncthreads();
    if (bl == b) {
#pragma unroll
      for (int mt = 0; mt < 2; ++mt)
#pragma unroll
        for (int kk = 0; kk < 4; ++kk) {
          xh[mt][kk] = ld_frag8(lds + ((mt << 4) + col) * 132 + (kk << 5) + (quad << 3));
          xl[mt][kk] = ld_frag8(lds + 4224 + ((mt << 4) + col) * 132 + (kk << 5) + (quad << 3));
        }
    }
    __syncthreads();
  }

  const long batch = (long)blockIdx.x * 2 + bl;
  const f32x4 zero = {0.f, 0.f, 0.f, 0.f};
  f32x4 oacc[8];
#pragma unroll
  for (int i = 0; i < 8; ++i) oacc[i] = zero;

  unsigned short* Kh = lds + OFF_K_HI + bl * 1152;
  unsigned short* Kl = lds + OFF_K_LO + bl * 1152;
  unsigned short* Vh = lds + OFF_VT_HI + bl * 1152;
  unsigned short* Vl = lds + OFF_VT_LO + bl * 1152;
  unsigned short* Qh = lds + OFF_Q_HI + bl * 1152;   // full [32][36] per batch
  unsigned short* Ql = lds + OFF_Q_LO + bl * 1152;
  unsigned short* Abuf = lds + OFF_A + bl * 1152;

  for (int hh = 0; hh < 4; ++hh) {
    // T0: prev head's wo reads retired -> stage wq
    SYNC_LDS();
    stage4(wsb + (hh << 13), lds, widu, lane);              // wq(h)
    SYNC_VM();

    // ======== Q = x * WqT (N-split: all 32 rows x 16-col half) ========
    f32x4 c0 = zero, c1 = zero;
    __builtin_amdgcn_s_setprio(1);
    projNS(lds, col, quad, hw, xh, xl, c0, c1);
    __builtin_amdgcn_s_setprio(0);

    SYNC_LDS();                                             // wq reads retired
    stage4(wsb + ((4 + hh) << 13), lds, widu, lane);        // wk
#pragma unroll
    for (int mt = 0; mt < 2; ++mt) {                        // writeback Q
      f32x4& c = mt ? c1 : c0;
#pragma unroll
      for (int r = 0; r < 4; ++r) {
        int row = (mt << 4) + (quad << 2) + r;
        wb_pair(Qh + row * 36 + sbase + col, Ql + row * 36 + sbase + col, c[r]);
      }
    }
    SYNC_VM();                                              // publishes Q + wk staged

    // ======== K = x * WkT ========
    c0 = zero; c1 = zero;
    __builtin_amdgcn_s_setprio(1);
    projNS(lds, col, quad, hw, xh, xl, c0, c1);
    __builtin_amdgcn_s_setprio(0);

    SYNC_LDS();
    stage4(wsb + ((8 + hh) << 13), lds, widu, lane);        // wv
#pragma unroll
    for (int mt = 0; mt < 2; ++mt) {                        // writeback K [t][d]
      f32x4& c = mt ? c1 : c0;
#pragma unroll
      for (int r = 0; r < 4; ++r) {
        int row = (mt << 4) + (quad << 2) + r;              // t
        wb_pair(Kh + row * 36 + sbase + col, Kl + row * 36 + sbase + col, c[r]);
      }
    }
    SYNC_VM();                                              // publishes K + wv staged

    // ======== V = x * WvT, stored V^T[d][t]; packed b64 writeback ========
    c0 = zero; c1 = zero;
    __builtin_amdgcn_s_setprio(1);
    projNS(lds, col, quad, hw, xh, xl, c0, c1);
    __builtin_amdgcn_s_setprio(0);

    SYNC_LDS();
    stage4(wsb + ((12 + hh) << 13), lds, widu, lane);       // wo
#pragma unroll
    for (int mt = 0; mt < 2; ++mt) {                        // V^T: d=sbase+col, t=mt*16+quad*4+r
      f32x4& c = mt ? c1 : c0;
      __bf16 h0 = (__bf16)c[0], h1 = (__bf16)c[1], h2 = (__bf16)c[2], h3 = (__bf16)c[3];
      bf16x2 hp0 = {h0, h1}, hp1 = {h2, h3};
      bf16x2 lp0 = {(__bf16)(c[0] - (float)h0), (__bf16)(c[1] - (float)h1)};
      bf16x2 lp1 = {(__bf16)(c[2] - (float)h2), (__bf16)(c[3] - (float)h3)};
      int off = (sbase + col) * 36 + (mt << 4) + (quad << 2);
      *(uint2*)(Vh + off) = make_uint2(__builtin_bit_cast(unsigned int, hp0),
                                       __builtin_bit_cast(unsigned int, hp1));
      *(uint2*)(Vl + off) = make_uint2(__builtin_bit_cast(unsigned int, lp0),
                                       __builtin_bit_cast(unsigned int, lp1));
    }

    // ======== scores = Q*K^T (M-split: rows sbase..; overlaps wo flight) ====
    f32x4 s0 = zero, s1 = zero;
    {
      bf16x8 qhf = ld_frag8(Qh + (sbase + col) * 36 + (quad << 3));
      bf16x8 qlf = ld_frag8(Ql + (sbase + col) * 36 + (quad << 3));
      bf16x8 k0 = ld_frag8(Kh + col * 36 + (quad << 3));
      bf16x8 k1 = ld_frag8(Kh + (col + 16) * 36 + (quad << 3));
      bf16x8 k0l = ld_frag8(Kl + col * 36 + (quad << 3));
      bf16x8 k1l = ld_frag8(Kl + (col + 16) * 36 + (quad << 3));
      s0 = mfma16(qhf, k0, s0); s0 = mfma16(qlf, k0, s0); s0 = mfma16(qhf, k0l, s0);
      s1 = mfma16(qhf, k1, s1); s1 = mfma16(qlf, k1, s1); s1 = mfma16(qhf, k1l, s1);
    }
    // ======== softmax over t (DPP 16-lane reduce, no LDS) ========
    float a0[4], a1[4];
#pragma unroll
    for (int r = 0; r < 4; ++r) {
      float v0 = s0[r], v1 = s1[r];
      float mx = rowmax16(fmaxf(v0, v1));
      float e0 = __expf(v0 - mx), e1 = __expf(v1 - mx);
      float sm = rowsum16(e0 + e1);
      float inv = 1.0f / sm;
      a0[r] = e0 * inv; a1[r] = e1 * inv;
    }
#pragma unroll
    for (int r = 0; r < 4; ++r) {                           // A rows sbase.. (own)
      int row = sbase + (quad << 2) + r;
      Abuf[row * 36 + col] = f2bf(a0[r]);
      Abuf[row * 36 + col + 16] = f2bf(a1[r]);
    }
    SYNC_VM();                                              // publishes V^T + A-not-needed + wo staged

    // ======== Hd = A * V (M-split rows sbase..) ========
    f32x4 hv0 = zero, hv1 = zero;
    {
      bf16x8 af = ld_frag8(Abuf + (sbase + col) * 36 + (quad << 3));
      bf16x8 v0h = ld_frag8(Vh + col * 36 + (quad << 3));
      bf16x8 v1h = ld_frag8(Vh + (col + 16) * 36 + (quad << 3));
      bf16x8 v0l = ld_frag8(Vl + col * 36 + (quad << 3));
      bf16x8 v1l = ld_frag8(Vl + (col + 16) * 36 + (quad << 3));
      hv0 = mfma16(af, v0h, hv0); hv0 = mfma16(af, v0l, hv0);
      hv1 = mfma16(af, v1h, hv1); hv1 = mfma16(af, v1l, hv1);
    }
#pragma unroll
    for (int r = 0; r < 4; ++r) {                           // Hd into dead Q rows (own rows sbase..)
      int row = sbase + (quad << 2) + r;
      wb_pair(Qh + row * 36 + col, Ql + row * 36 + col, hv0[r]);
      wb_pair(Qh + row * 36 + col + 16, Ql + row * 36 + col + 16, hv1[r]);
    }
    // ======== out += Hd * Wo (M-split rows sbase..) ========
    {
      bf16x8 dh = ld_frag8(Qh + (sbase + col) * 36 + (quad << 3));
      bf16x8 dl = ld_frag8(Ql + (sbase + col) * 36 + (quad << 3));
      int swzo = (quad ^ ((col >> 1) & 3)) << 3;
      __builtin_amdgcn_s_setprio(1);
#pragma unroll
      for (int t8 = 0; t8 < 8; ++t8) {
        const unsigned short* wp = lds + (((t8 << 4) + col) << 5) + swzo;
        bf16x8 wh = ld_frag16(wp);
        bf16x8 wl = ld_frag16(wp + 4096);
        oacc[t8] = mfma16(dh, wh, oacc[t8]);
        oacc[t8] = mfma16(dl, wh, oacc[t8]);
        oacc[t8] = mfma16(dh, wl, oacc[t8]);
      }
      __builtin_amdgcn_s_setprio(0);
    }
  }  // head loop

  // ---- store out [16 rows][128 cols] fp32 ----
  float* og = out + batch * 4096;
#pragma unroll
  for (int t8 = 0; t8 < 8; ++t8) {
#pragma unroll
    for (int r = 0; r < 4; ++r) {
      og[(sbase + (quad << 2) + r) * 128 + (t8 << 4) + col] = oacc[t8][r];
    }
  }
}

extern "C" void kernel_launch(void* const* d_in, const int* in_sizes, int n_in,
                              void* d_out, int out_size, void* d_ws, size_t ws_size,
                              hipStream_t stream) {
  const float* x = (const float*)d_in[0];
  const float* wq = (const float*)d_in[1];
  const float* wk = (const float*)d_in[2];
  const float* wv = (const float*)d_in[3];
  const float* wo = (const float*)d_in[4];
  float* out = (float*)d_out;
  unsigned short* wsb = (unsigned short*)d_ws;  // needs 262144 B
  hipLaunchKernelGGL(prep_w, dim3(256), dim3(256), 0, stream, wq, wk, wv, wo, wsb);
  hipLaunchKernelGGL(attn_fused, dim3(8192), dim3(256), 0, stream, x, wsb, out);
}